// Round 11
// baseline (98.772 us; speedup 1.0000x reference)
//
#include <hip/hip_runtime.h>
#include <hip/hip_bf16.h>

typedef __attribute__((ext_vector_type(8))) short bf16x8;
typedef __attribute__((ext_vector_type(4))) float f32x4;
typedef __attribute__((ext_vector_type(4))) unsigned u32x4;
typedef __attribute__((ext_vector_type(2))) unsigned u32x2;

#define T_LEN 2048
#define S_ENC 256
#define QSCALE 0.18033688011112042f     // 64^-0.5 * log2(e): softmax in log2 domain

// R10's hand-rolled {asm lgkmcnt(0); s_barrier} raced (absmax 0.16):
// s_barrier builtin is NOT a compiler memory fence and the asm clobber only
// fences one side. Use the compiler-blessed __syncthreads(); its vmcnt(0)
// drain is covered here because prefetch loads are issued a full
// compute-phase (~2500 cyc) before the barrier.
#define BARRIER() __syncthreads()

__device__ __forceinline__ float exp2_hw(float x) {
#if __has_builtin(__builtin_amdgcn_exp2f)
  return __builtin_amdgcn_exp2f(x);
#else
  float r;
  asm("v_exp_f32 %0, %1" : "=v"(r) : "v"(x));
  return r;
#endif
}

// hardware packed f32->bf16 (RNE), 2 values per instruction
__device__ __forceinline__ unsigned cvt_pk_bf16(float lo, float hi) {
  unsigned r;
  asm("v_cvt_pk_bf16_f32 %0, %1, %2" : "=v"(r) : "v"(lo), "v"(hi));
  return r;
}

__device__ __forceinline__ short f2bf(float x) {   // cold path (Q frag) only
  union { __hip_bfloat16 b; short s; } u;
  u.b = __float2bfloat16(x);
  return u.s;
}

// XOR bank swizzle (T2, verified: conflicts 9.4M -> 0): rows of 64 shorts
// (128B), 16B-slot index ^= row&7. Applied on BOTH write and read sides.
__device__ __forceinline__ int swz(int row, int col) {
  return row * 64 + (col ^ ((row & 7) << 3));
}

union PU { u32x4 u; bf16x8 b; };

// ---- staging (R9-verbatim index math, split into issue / write halves) ----
template<int STRIDE>
__device__ __forceinline__ void issue_loads(
    const float* __restrict__ kb, const float* __restrict__ vb, int s0, int tid,
    float (&kr)[8], float (&kr2)[8], f32x4 (&vr)[4]) {
  const int ks = tid & 63;
  const int kc = (tid >> 6) * 8;
  const float* kp = kb + (size_t)kc * STRIDE + (s0 + ks);
  const float* kp2 = kp + (size_t)32 * STRIDE;
#pragma unroll
  for (int r = 0; r < 8; ++r) kr[r] = kp[(size_t)r * STRIDE];
#pragma unroll
  for (int r = 0; r < 8; ++r) kr2[r] = kp2[(size_t)r * STRIDE];
  const int vg = tid & 15;
  const int vc = tid >> 4;
  const float* vp0 = vb + (size_t)vc * STRIDE + (s0 + 4 * vg);
  vr[0] = *(const f32x4*)(vp0);
  vr[1] = *(const f32x4*)(vp0 + (size_t)32 * STRIDE);
  vr[2] = *(const f32x4*)(vp0 + (size_t)16 * STRIDE);
  vr[3] = *(const f32x4*)(vp0 + (size_t)48 * STRIDE);
}

__device__ __forceinline__ void stage_write(
    short* __restrict__ Kt, short* __restrict__ Vt, int tid,
    const float (&kr)[8], const float (&kr2)[8], const f32x4 (&vr)[4]) {
  const int ks = tid & 63;
  const int kc = (tid >> 6) * 8;
  u32x4 kw;
#pragma unroll
  for (int r = 0; r < 4; ++r) kw[r] = cvt_pk_bf16(kr[2 * r], kr[2 * r + 1]);
  *(u32x4*)(Kt + swz(ks, kc)) = kw;
  u32x4 kw2;
#pragma unroll
  for (int r = 0; r < 4; ++r) kw2[r] = cvt_pk_bf16(kr2[2 * r], kr2[2 * r + 1]);
  *(u32x4*)(Kt + swz(ks, kc + 32)) = kw2;

  const int vg = tid & 15;
  const int vc = tid >> 4;
  const int vcol = 32 * (vg >> 3) + 8 * (vg & 3) + 4 * ((vg >> 2) & 1);  // sigma-perm
  const int vrow[4] = {vc, vc + 32, vc + 16, vc + 48};
#pragma unroll
  for (int i = 0; i < 4; ++i) {
    u32x2 vw;
    vw[0] = cvt_pk_bf16(vr[i][0], vr[i][1]);
    vw[1] = cvt_pk_bf16(vr[i][2], vr[i][3]);
    *(u32x2*)(Vt + swz(vrow[i], vcol)) = vw;
  }
}

// ---- compute (R9 verbatim): qt=4, K-frags hoisted, softmax in qt-pairs ----
__device__ __forceinline__ void compute_tile(
    const short* __restrict__ Kt, const short* __restrict__ Vt,
    const bf16x8 (&qf)[4][2], f32x4 (&o)[4][4], float (&lp)[4], int tid) {
  const int lane = tid & 63;
  const int ln = lane & 15;
  const int lg = lane >> 4;

  bf16x8 kf[4][2];
#pragma unroll
  for (int mt = 0; mt < 4; ++mt) {
    const int row = 16 * mt + ln;
    kf[mt][0] = *(const bf16x8*)(Kt + swz(row, 8 * lg));
    kf[mt][1] = *(const bf16x8*)(Kt + swz(row, 32 + 8 * lg));
  }

  PU pfrag[4][2];
#pragma unroll
  for (int pr = 0; pr < 2; ++pr) {
    f32x4 sacc[2][4];
#pragma unroll
    for (int q2 = 0; q2 < 2; ++q2)
#pragma unroll
      for (int mt = 0; mt < 4; ++mt) sacc[q2][mt] = (f32x4){0.f, 0.f, 0.f, 0.f};

#pragma unroll
    for (int mt = 0; mt < 4; ++mt)
#pragma unroll
      for (int q2 = 0; q2 < 2; ++q2) {
        const int qt = 2 * pr + q2;
        sacc[q2][mt] = __builtin_amdgcn_mfma_f32_16x16x32_bf16(kf[mt][0], qf[qt][0], sacc[q2][mt], 0, 0, 0);
        sacc[q2][mt] = __builtin_amdgcn_mfma_f32_16x16x32_bf16(kf[mt][1], qf[qt][1], sacc[q2][mt], 0, 0, 0);
      }

#pragma unroll
    for (int q2 = 0; q2 < 2; ++q2) {
      const int qt = 2 * pr + q2;
      float pmt[4];
#pragma unroll
      for (int mt = 0; mt < 4; ++mt) {
        float p0 = exp2_hw(sacc[q2][mt][0]);
        float p1 = exp2_hw(sacc[q2][mt][1]);
        float p2 = exp2_hw(sacc[q2][mt][2]);
        float p3 = exp2_hw(sacc[q2][mt][3]);
        pfrag[qt][mt >> 1].u[2 * (mt & 1) + 0] = cvt_pk_bf16(p0, p1);
        pfrag[qt][mt >> 1].u[2 * (mt & 1) + 1] = cvt_pk_bf16(p2, p3);
        pmt[mt] = (p0 + p1) + (p2 + p3);
      }
      lp[qt] += (pmt[0] + pmt[1]) + (pmt[2] + pmt[3]);
    }
  }

#pragma unroll
  for (int sub = 0; sub < 2; ++sub)
#pragma unroll
    for (int ct = 0; ct < 4; ++ct) {
      const bf16x8 vf = *(const bf16x8*)(Vt + swz(16 * ct + ln, 32 * sub + 8 * lg));
#pragma unroll
      for (int qt = 0; qt < 4; ++qt)
        o[qt][ct] = __builtin_amdgcn_mfma_f32_16x16x32_bf16(vf, pfrag[qt][sub].b, o[qt][ct], 0, 0, 0);
    }
}

__global__ __launch_bounds__(256, 2) void attn_kernel(
    const float* __restrict__ qkv, const float* __restrict__ ekv,
    float* __restrict__ out) {
  const int tid = threadIdx.x;
  const int lane = tid & 63;
  const int wave = tid >> 6;              // 0..3
  const int ln = lane & 15;
  const int lg = lane >> 4;

  // XCD swizzle (verified: FETCH 315->74 MB): all 8 q-blocks of one head
  // land on the same XCD (blk%8 == bh%8 for all of them)
  const int bh = blockIdx.x & 63;
  const int qb = blockIdx.x >> 6;         // 0..7
  const int t0 = qb * 256 + wave * 64;    // this wave: queries t0 .. t0+63

  const float* qp  = qkv + (size_t)bh * 192 * T_LEN;
  const float* kp  = qp + (size_t)64 * T_LEN;
  const float* vp  = qp + (size_t)128 * T_LEN;
  const float* ekp = ekv + (size_t)bh * 128 * S_ENC;
  const float* evp = ekp + (size_t)64 * S_ENC;

  // double-buffered tiles: 2 x (8 KB K + 8 KB V) = 32 KB/block
  __shared__ __attribute__((aligned(16))) short Kt[2][64 * 64];
  __shared__ __attribute__((aligned(16))) short Vt[2][64 * 64];

  // Q fragments (channel mapping 32*kk + 8*lg + j, matching K-frag reads)
  bf16x8 qf[4][2];
#pragma unroll
  for (int qt = 0; qt < 4; ++qt)
#pragma unroll
    for (int kk = 0; kk < 2; ++kk)
#pragma unroll
      for (int j = 0; j < 8; ++j)
        qf[qt][kk][j] =
            f2bf(qp[(size_t)(32 * kk + 8 * lg + j) * T_LEN + (t0 + 16 * qt + ln)] * QSCALE);

  f32x4 o[4][4];
#pragma unroll
  for (int qt = 0; qt < 4; ++qt)
#pragma unroll
    for (int ct = 0; ct < 4; ++ct) o[qt][ct] = (f32x4){0.f, 0.f, 0.f, 0.f};
  float lp[4] = {0.f, 0.f, 0.f, 0.f};

  // ---- encoder phase: 4 tiles, two-barrier structure (buf 0 only) ----
  for (int st = 0; st < 4; ++st) {
    float kr[8], kr2[8];
    f32x4 vr[4];
    issue_loads<S_ENC>(ekp, evp, 64 * st, tid, kr, kr2, vr);
    BARRIER();   // prior tile's LDS reads complete
    stage_write(&Kt[0][0], &Vt[0][0], tid, kr, kr2, vr);
    BARRIER();   // tile staged
    compute_tile(&Kt[0][0], &Vt[0][0], qf, o, lp, tid);
  }

  // ---- self phase: 32 tiles, single-barrier double-buffered pipeline ----
  {
    float kr[8], kr2[8];
    f32x4 vr[4];
    // prologue: stage tile 0 into buf0, prefetch tile 1 into registers
    issue_loads<T_LEN>(kp, vp, 0, tid, kr, kr2, vr);
    BARRIER();   // enc tile 3's LDS reads complete
    stage_write(&Kt[0][0], &Vt[0][0], tid, kr, kr2, vr);
    issue_loads<T_LEN>(kp, vp, 64, tid, kr, kr2, vr);
    BARRIER();   // buf0 visible

    int cur = 0;
#pragma unroll 1
    for (int t = 0; t < 31; ++t) {
      // stage tile t+1 into the buffer whose reads finished at the last barrier
      stage_write(&Kt[cur ^ 1][0], &Vt[cur ^ 1][0], tid, kr, kr2, vr);
      if (t < 30)
        issue_loads<T_LEN>(kp, vp, 64 * (t + 2), tid, kr, kr2, vr);
      compute_tile(&Kt[cur][0], &Vt[cur][0], qf, o, lp, tid);  // tile t
      BARRIER();   // writes of t+1 visible, reads of t drained
      cur ^= 1;
    }
    compute_tile(&Kt[cur][0], &Vt[cur][0], qf, o, lp, tid);    // tile 31
  }

  // ---- epilogue: reduce l across the 4 lane-groups, normalize, store O^T ----
#pragma unroll
  for (int qt = 0; qt < 4; ++qt) {
    float l = lp[qt];
    l += __shfl_xor(l, 16);
    l += __shfl_xor(l, 32);
    const float inv = 1.0f / l;
    float* ob = out + (size_t)bh * 64 * T_LEN + (t0 + 16 * qt + ln);
#pragma unroll
    for (int ct = 0; ct < 4; ++ct)
#pragma unroll
      for (int r = 0; r < 4; ++r)
        ob[(size_t)(16 * ct + 4 * lg + r) * T_LEN] = o[qt][ct][r] * inv;
  }
}

extern "C" void kernel_launch(void* const* d_in, const int* in_sizes, int n_in,
                              void* d_out, int out_size, void* d_ws, size_t ws_size,
                              hipStream_t stream) {
  const float* qkv = (const float*)d_in[0];
  const float* ekv = (const float*)d_in[1];
  float* out = (float*)d_out;
  attn_kernel<<<dim3(512), dim3(256), 0, stream>>>(qkv, ekv, out);
}

// Round 12
// 91.780 us; speedup vs baseline: 1.0762x; 1.0762x over previous
//
#include <hip/hip_runtime.h>
#include <hip/hip_bf16.h>

typedef __attribute__((ext_vector_type(8))) short bf16x8;
typedef __attribute__((ext_vector_type(4))) float f32x4;
typedef __attribute__((ext_vector_type(4))) unsigned u32x4;
typedef __attribute__((ext_vector_type(2))) unsigned u32x2;

#define T_LEN 2048
#define S_ENC 256
#define QSCALE 0.18033688011112042f     // 64^-0.5 * log2(e): softmax in log2 domain
#define BARRIER() __syncthreads()

__device__ __forceinline__ float exp2_hw(float x) {
#if __has_builtin(__builtin_amdgcn_exp2f)
  return __builtin_amdgcn_exp2f(x);
#else
  float r;
  asm("v_exp_f32 %0, %1" : "=v"(r) : "v"(x));
  return r;
#endif
}

// hardware packed f32->bf16 (RNE), 2 values per instruction
__device__ __forceinline__ unsigned cvt_pk_bf16(float lo, float hi) {
  unsigned r;
  asm("v_cvt_pk_bf16_f32 %0, %1, %2" : "=v"(r) : "v"(lo), "v"(hi));
  return r;
}

__device__ __forceinline__ short f2bf(float x) {   // cold path (Q frag) only
  union { __hip_bfloat16 b; short s; } u;
  u.b = __float2bfloat16(x);
  return u.s;
}

// XOR bank swizzle (T2, verified: conflicts 9.4M -> 0): rows of 64 shorts
// (128B), 16B-slot index ^= row&7. Applied on BOTH write and read sides.
__device__ __forceinline__ int swz(int row, int col) {
  return row * 64 + (col ^ ((row & 7) << 3));
}

union PU { u32x4 u; bf16x8 b; };

// ---- staging (R9-verbatim) ----
template<int STRIDE>
__device__ __forceinline__ void issue_loads(
    const float* __restrict__ kb, const float* __restrict__ vb, int s0, int tid,
    float (&kr)[8], float (&kr2)[8], f32x4 (&vr)[4]) {
  const int ks = tid & 63;
  const int kc = (tid >> 6) * 8;
  const float* kp = kb + (size_t)kc * STRIDE + (s0 + ks);
  const float* kp2 = kp + (size_t)32 * STRIDE;
#pragma unroll
  for (int r = 0; r < 8; ++r) kr[r] = kp[(size_t)r * STRIDE];
#pragma unroll
  for (int r = 0; r < 8; ++r) kr2[r] = kp2[(size_t)r * STRIDE];
  const int vg = tid & 15;
  const int vc = tid >> 4;
  const float* vp0 = vb + (size_t)vc * STRIDE + (s0 + 4 * vg);
  vr[0] = *(const f32x4*)(vp0);
  vr[1] = *(const f32x4*)(vp0 + (size_t)32 * STRIDE);
  vr[2] = *(const f32x4*)(vp0 + (size_t)16 * STRIDE);
  vr[3] = *(const f32x4*)(vp0 + (size_t)48 * STRIDE);
}

__device__ __forceinline__ void stage_write(
    short* __restrict__ Kt, short* __restrict__ Vt, int tid,
    const float (&kr)[8], const float (&kr2)[8], const f32x4 (&vr)[4]) {
  const int ks = tid & 63;
  const int kc = (tid >> 6) * 8;
  u32x4 kw;
#pragma unroll
  for (int r = 0; r < 4; ++r) kw[r] = cvt_pk_bf16(kr[2 * r], kr[2 * r + 1]);
  *(u32x4*)(Kt + swz(ks, kc)) = kw;
  u32x4 kw2;
#pragma unroll
  for (int r = 0; r < 4; ++r) kw2[r] = cvt_pk_bf16(kr2[2 * r], kr2[2 * r + 1]);
  *(u32x4*)(Kt + swz(ks, kc + 32)) = kw2;

  const int vg = tid & 15;
  const int vc = tid >> 4;
  const int vcol = 32 * (vg >> 3) + 8 * (vg & 3) + 4 * ((vg >> 2) & 1);  // sigma-perm
  const int vrow[4] = {vc, vc + 32, vc + 16, vc + 48};
#pragma unroll
  for (int i = 0; i < 4; ++i) {
    u32x2 vw;
    vw[0] = cvt_pk_bf16(vr[i][0], vr[i][1]);
    vw[1] = cvt_pk_bf16(vr[i][2], vr[i][3]);
    *(u32x2*)(Vt + swz(vrow[i], vcol)) = vw;
  }
}

// softmax for one q-subtile: p = 2^s, pack to bf16 pfrag, accumulate l
__device__ __forceinline__ void softmax_qt(const f32x4 (&sa)[4], PU (&pf)[2],
                                           float& lpq) {
  float pmt[4];
#pragma unroll
  for (int mt = 0; mt < 4; ++mt) {
    float p0 = exp2_hw(sa[mt][0]);
    float p1 = exp2_hw(sa[mt][1]);
    float p2 = exp2_hw(sa[mt][2]);
    float p3 = exp2_hw(sa[mt][3]);
    pf[mt >> 1].u[2 * (mt & 1) + 0] = cvt_pk_bf16(p0, p1);
    pf[mt >> 1].u[2 * (mt & 1) + 1] = cvt_pk_bf16(p2, p3);
    pmt[mt] = (p0 + p1) + (p2 + p3);
  }
  lpq += (pmt[0] + pmt[1]) + (pmt[2] + pmt[3]);
}

// ---- compute, reordered for trans||MFMA overlap:
// QK01 -> sm01 -> QK23 -> {PV01.sub0 | sm2} -> {PV01.sub1 | sm3} -> PV23 ----
__device__ __forceinline__ void compute_tile(
    const short* __restrict__ Kt, const short* __restrict__ Vt,
    const bf16x8 (&qf)[4][2], f32x4 (&o)[4][4], float (&lp)[4], int tid) {
  const int lane = tid & 63;
  const int ln = lane & 15;
  const int lg = lane >> 4;

  bf16x8 kf[4][2];
#pragma unroll
  for (int mt = 0; mt < 4; ++mt) {
    const int row = 16 * mt + ln;
    kf[mt][0] = *(const bf16x8*)(Kt + swz(row, 8 * lg));
    kf[mt][1] = *(const bf16x8*)(Kt + swz(row, 32 + 8 * lg));
  }

  // QK pair0 (qt 0,1)
  f32x4 sa[2][4];
#pragma unroll
  for (int q2 = 0; q2 < 2; ++q2)
#pragma unroll
    for (int mt = 0; mt < 4; ++mt) sa[q2][mt] = (f32x4){0.f, 0.f, 0.f, 0.f};
#pragma unroll
  for (int mt = 0; mt < 4; ++mt)
#pragma unroll
    for (int q2 = 0; q2 < 2; ++q2) {
      sa[q2][mt] = __builtin_amdgcn_mfma_f32_16x16x32_bf16(kf[mt][0], qf[q2][0], sa[q2][mt], 0, 0, 0);
      sa[q2][mt] = __builtin_amdgcn_mfma_f32_16x16x32_bf16(kf[mt][1], qf[q2][1], sa[q2][mt], 0, 0, 0);
    }

  // sm pair0
  PU pf0[2][2];
  softmax_qt(sa[0], pf0[0], lp[0]);
  softmax_qt(sa[1], pf0[1], lp[1]);

  // QK pair1 (qt 2,3) -- reuse sa
#pragma unroll
  for (int q2 = 0; q2 < 2; ++q2)
#pragma unroll
    for (int mt = 0; mt < 4; ++mt) sa[q2][mt] = (f32x4){0.f, 0.f, 0.f, 0.f};
#pragma unroll
  for (int mt = 0; mt < 4; ++mt)
#pragma unroll
    for (int q2 = 0; q2 < 2; ++q2) {
      sa[q2][mt] = __builtin_amdgcn_mfma_f32_16x16x32_bf16(kf[mt][0], qf[2 + q2][0], sa[q2][mt], 0, 0, 0);
      sa[q2][mt] = __builtin_amdgcn_mfma_f32_16x16x32_bf16(kf[mt][1], qf[2 + q2][1], sa[q2][mt], 0, 0, 0);
    }

  // PV pair0 sub0 (MFMA pipe)  ||  sm2 (trans pipe) -- independent streams
  bf16x8 vf[2][4];
  PU pf1[2][2];
#pragma unroll
  for (int ct = 0; ct < 4; ++ct) {
    vf[0][ct] = *(const bf16x8*)(Vt + swz(16 * ct + ln, 8 * lg));
    o[0][ct] = __builtin_amdgcn_mfma_f32_16x16x32_bf16(vf[0][ct], pf0[0][0].b, o[0][ct], 0, 0, 0);
    o[1][ct] = __builtin_amdgcn_mfma_f32_16x16x32_bf16(vf[0][ct], pf0[1][0].b, o[1][ct], 0, 0, 0);
  }
  softmax_qt(sa[0], pf1[0], lp[2]);

  // PV pair0 sub1  ||  sm3
#pragma unroll
  for (int ct = 0; ct < 4; ++ct) {
    vf[1][ct] = *(const bf16x8*)(Vt + swz(16 * ct + ln, 32 + 8 * lg));
    o[0][ct] = __builtin_amdgcn_mfma_f32_16x16x32_bf16(vf[1][ct], pf0[0][1].b, o[0][ct], 0, 0, 0);
    o[1][ct] = __builtin_amdgcn_mfma_f32_16x16x32_bf16(vf[1][ct], pf0[1][1].b, o[1][ct], 0, 0, 0);
  }
  softmax_qt(sa[1], pf1[1], lp[3]);

  // PV pair1 (vf reused from registers)
#pragma unroll
  for (int sub = 0; sub < 2; ++sub)
#pragma unroll
    for (int ct = 0; ct < 4; ++ct) {
      o[2][ct] = __builtin_amdgcn_mfma_f32_16x16x32_bf16(vf[sub][ct], pf1[0][sub].b, o[2][ct], 0, 0, 0);
      o[3][ct] = __builtin_amdgcn_mfma_f32_16x16x32_bf16(vf[sub][ct], pf1[1][sub].b, o[3][ct], 0, 0, 0);
    }
}

__global__ __launch_bounds__(256, 2) void attn_kernel(
    const float* __restrict__ qkv, const float* __restrict__ ekv,
    float* __restrict__ out) {
  const int tid = threadIdx.x;
  const int lane = tid & 63;
  const int wave = tid >> 6;              // 0..3
  const int ln = lane & 15;
  const int lg = lane >> 4;

  // XCD swizzle (verified: FETCH 315->74 MB): all 8 q-blocks of one head
  // land on the same XCD (blk%8 == bh%8 for all of them)
  const int bh = blockIdx.x & 63;
  const int qb = blockIdx.x >> 6;         // 0..7
  const int t0 = qb * 256 + wave * 64;    // this wave: queries t0 .. t0+63

  const float* qp  = qkv + (size_t)bh * 192 * T_LEN;
  const float* kp  = qp + (size_t)64 * T_LEN;
  const float* vp  = qp + (size_t)128 * T_LEN;
  const float* ekp = ekv + (size_t)bh * 128 * S_ENC;
  const float* evp = ekp + (size_t)64 * S_ENC;

  __shared__ __attribute__((aligned(16))) short Kt[64 * 64];
  __shared__ __attribute__((aligned(16))) short Vt[64 * 64];

  // Q fragments (channel mapping 32*kk + 8*lg + j, matching K-frag reads)
  bf16x8 qf[4][2];
#pragma unroll
  for (int qt = 0; qt < 4; ++qt)
#pragma unroll
    for (int kk = 0; kk < 2; ++kk)
#pragma unroll
      for (int j = 0; j < 8; ++j)
        qf[qt][kk][j] =
            f2bf(qp[(size_t)(32 * kk + 8 * lg + j) * T_LEN + (t0 + 16 * qt + ln)] * QSCALE);

  f32x4 o[4][4];
#pragma unroll
  for (int qt = 0; qt < 4; ++qt)
#pragma unroll
    for (int ct = 0; ct < 4; ++ct) o[qt][ct] = (f32x4){0.f, 0.f, 0.f, 0.f};
  float lp[4] = {0.f, 0.f, 0.f, 0.f};

  for (int st = 0; st < 4; ++st) {
    float kr[8], kr2[8];
    f32x4 vr[4];
    issue_loads<S_ENC>(ekp, evp, 64 * st, tid, kr, kr2, vr);
    BARRIER();   // prior tile's LDS reads complete
    stage_write(Kt, Vt, tid, kr, kr2, vr);
    BARRIER();   // tile staged
    compute_tile(Kt, Vt, qf, o, lp, tid);
  }
  for (int st = 0; st < 32; ++st) {
    float kr[8], kr2[8];
    f32x4 vr[4];
    issue_loads<T_LEN>(kp, vp, 64 * st, tid, kr, kr2, vr);
    BARRIER();
    stage_write(Kt, Vt, tid, kr, kr2, vr);
    BARRIER();
    compute_tile(Kt, Vt, qf, o, lp, tid);
  }

  // ---- epilogue: reduce l across the 4 lane-groups, normalize, store O^T ----
#pragma unroll
  for (int qt = 0; qt < 4; ++qt) {
    float l = lp[qt];
    l += __shfl_xor(l, 16);
    l += __shfl_xor(l, 32);
    const float inv = 1.0f / l;
    float* ob = out + (size_t)bh * 64 * T_LEN + (t0 + 16 * qt + ln);
#pragma unroll
    for (int ct = 0; ct < 4; ++ct)
#pragma unroll
      for (int r = 0; r < 4; ++r)
        ob[(size_t)(16 * ct + 4 * lg + r) * T_LEN] = o[qt][ct][r] * inv;
  }
}

extern "C" void kernel_launch(void* const* d_in, const int* in_sizes, int n_in,
                              void* d_out, int out_size, void* d_ws, size_t ws_size,
                              hipStream_t stream) {
  const float* qkv = (const float*)d_in[0];
  const float* ekv = (const float*)d_in[1];
  float* out = (float*)d_out;
  attn_kernel<<<dim3(512), dim3(256), 0, stream>>>(qkv, ekv, out);
}